// Round 2
// baseline (193.468 us; speedup 1.0000x reference)
//
#include <hip/hip_runtime.h>
#include <hip/hip_bf16.h>

// Fused: segment-mean neighbor aggregation (COO, sorted dst) + x + mean,
// then [64x128] @ W[128x128] + b, ReLU, fp32 out.
//
// Block = 256 threads (4 waves), handles BR=64 destination rows.
// Phase 0: 65 parallel binary searches for segment bounds (edge_dst sorted).
// Phase 1: wave w aggregates rows [16w,16w+16); lane owns feature pair.
// Phase 2: register-tiled fp32 GEMM: thread = 4 rows x 8 cols.

#define FD 128     // feature dim == out dim
#define BR 64      // rows per block
#define HS 130     // LDS h row stride (floats): bank-conflict-free phase 2

__global__ __launch_bounds__(256) void meanagg_fused_kernel(
    const float* __restrict__ x, const float* __restrict__ W,
    const float* __restrict__ bias, const int* __restrict__ esrc,
    const int* __restrict__ edst, float* __restrict__ out, int N, int E)
{
    __shared__ float sh[BR * HS];
    __shared__ int seg[BR + 1];

    const int t = threadIdx.x;
    const int base = blockIdx.x * BR;

    // ---- Phase 0: segment boundaries via lower_bound on sorted edge_dst ----
    if (t < BR + 1) {
        int v = base + t;
        int lo = 0, hi = E;
        while (lo < hi) {
            int mid = (lo + hi) >> 1;
            if (edst[mid] < v) lo = mid + 1; else hi = mid;
        }
        seg[t] = lo;
    }
    __syncthreads();

    // ---- Phase 1: aggregate h = x + segment_mean(x[src]) into LDS ----
    const int wave = t >> 6;
    const int lane = t & 63;
    for (int it = 0; it < 16; ++it) {
        int rb = wave * 16 + it;
        int r = base + rb;
        if (r >= N) break;   // uniform across wave (rows ascend)
        int s = seg[rb], e = seg[rb + 1];
        float sx = 0.f, sy = 0.f;
        for (int ed = s; ed < e; ++ed) {
            int src = esrc[ed];  // wave-uniform broadcast load
            float2 v = *(const float2*)(x + (size_t)src * FD + 2 * lane);
            sx += v.x; sy += v.y;
        }
        int deg = e - s;
        float inv = 1.0f / (float)(deg > 0 ? deg : 1);
        float2 xv = *(const float2*)(x + (size_t)r * FD + 2 * lane);
        float2 h2;
        h2.x = xv.x + sx * inv;
        h2.y = xv.y + sy * inv;
        *(float2*)(sh + rb * HS + 2 * lane) = h2;
    }
    __syncthreads();

    // ---- Phase 2: GEMM h[64][128] @ W[128][128] + b, ReLU ----
    const int cg = t & 15;   // column group: cols [8cg, 8cg+8)
    const int rg = t >> 4;   // row group: rows [4rg, 4rg+4)

    float acc[4][8];
#pragma unroll
    for (int i = 0; i < 4; ++i)
#pragma unroll
        for (int j = 0; j < 8; ++j) acc[i][j] = 0.f;

#pragma unroll 4
    for (int k = 0; k < FD; ++k) {
        float hv[4];
#pragma unroll
        for (int i = 0; i < 4; ++i) hv[i] = sh[(4 * rg + i) * HS + k];
        float4 w0 = *(const float4*)(W + k * FD + 8 * cg);
        float4 w1 = *(const float4*)(W + k * FD + 8 * cg + 4);
        float wv[8] = {w0.x, w0.y, w0.z, w0.w, w1.x, w1.y, w1.z, w1.w};
#pragma unroll
        for (int i = 0; i < 4; ++i)
#pragma unroll
            for (int j = 0; j < 8; ++j)
                acc[i][j] += hv[i] * wv[j];
    }

    float4 b0 = *(const float4*)(bias + 8 * cg);
    float4 b1 = *(const float4*)(bias + 8 * cg + 4);
    float bv[8] = {b0.x, b0.y, b0.z, b0.w, b1.x, b1.y, b1.z, b1.w};

#pragma unroll
    for (int i = 0; i < 4; ++i) {
        int r = base + 4 * rg + i;
        if (r >= N) continue;
        float o[8];
#pragma unroll
        for (int j = 0; j < 8; ++j) {
            float v = acc[i][j] + bv[j];
            o[j] = v > 0.f ? v : 0.f;
        }
        *(float4*)(out + (size_t)r * FD + 8 * cg) = make_float4(o[0], o[1], o[2], o[3]);
        *(float4*)(out + (size_t)r * FD + 8 * cg + 4) = make_float4(o[4], o[5], o[6], o[7]);
    }
}

extern "C" void kernel_launch(void* const* d_in, const int* in_sizes, int n_in,
                              void* d_out, int out_size, void* d_ws, size_t ws_size,
                              hipStream_t stream) {
    const float* x    = (const float*)d_in[0];
    const float* W    = (const float*)d_in[1];
    const float* bias = (const float*)d_in[2];
    const int* esrc   = (const int*)d_in[3];
    const int* edst   = (const int*)d_in[4];
    float* out        = (float*)d_out;

    int N = in_sizes[0] / FD;
    int E = in_sizes[3];

    int blocks = (N + BR - 1) / BR;
    meanagg_fused_kernel<<<blocks, 256, 0, stream>>>(x, W, bias, esrc, edst, out, N, E);
}

// Round 5
// 114.628 us; speedup vs baseline: 1.6878x; 1.6878x over previous
//
#include <hip/hip_runtime.h>
#include <hip/hip_bf16.h>

// Fused: segment-mean neighbor aggregation (COO, sorted dst) + x + mean,
// then [64x128] @ W[128x128] + b, ReLU, fp32 out.
//
// Block = 256 threads (4 waves), BR=64 rows.
// Phase 0: 65 parallel binary searches for segment bounds (edge_dst sorted).
// Phase 1 (latency-optimized): half-wave (32 lanes) per row, float4/lane.
//   - one coalesced esrc batch-load per row (up to 32 indices, ONE latency),
//     __shfl broadcast per edge (VALU, no memory latency)
//   - 4-deep edge unroll with independent float4 accumulators (4 loads in flight)
//   - next row's esrc batch + x self-read software-pipelined ahead
// Phase 2: register-tiled fp32 GEMM: thread = 4 rows x 8 cols.

#define FD 128     // feature dim == out dim
#define BR 64      // rows per block
#define HS 132     // LDS h row stride: 16B-aligned float4 rows; phase-2 2-way max (free)

__global__ __launch_bounds__(256) void meanagg_fused_kernel(
    const float* __restrict__ x, const float* __restrict__ W,
    const float* __restrict__ bias, const int* __restrict__ esrc,
    const int* __restrict__ edst, float* __restrict__ out, int N, int E)
{
    __shared__ float sh[BR * HS];   // 33792 B
    __shared__ int seg[BR + 1];

    const int t = threadIdx.x;
    const int base = blockIdx.x * BR;

    // ---- Phase 0: segment boundaries via lower_bound on sorted edge_dst ----
    if (t < BR + 1) {
        int v = base + t;
        int lo = 0, hi = E;
        while (lo < hi) {
            int mid = (lo + hi) >> 1;
            if (edst[mid] < v) lo = mid + 1; else hi = mid;
        }
        seg[t] = lo;
    }
    __syncthreads();

    // ---- Phase 1: h = x + segment_mean(x[src]) into LDS ----
    const int wave = t >> 6;
    const int lane = t & 63;
    const int sw = lane >> 5;      // subwave (row within pair)
    const int sl = lane & 31;      // sublane: owns features [4sl, 4sl+4)
    const int lb = sw << 5;        // shfl lane base for this subwave
    const int rowbase = wave * 16;

    // prologue: prefetch iteration 0
    int rb = rowbase + sw;
    int r  = base + rb;
    int s  = (r < N) ? seg[rb] : 0;
    int e  = (r < N) ? seg[rb + 1] : 0;
    int src_next = (s + sl < e) ? esrc[s + sl] : 0;
    float4 xv_next = make_float4(0.f, 0.f, 0.f, 0.f);
    if (r < N) xv_next = *(const float4*)(x + (size_t)r * FD + 4 * sl);

    for (int it = 0; it < 8; ++it) {
        const int cur_rb = rowbase + it * 2 + sw;
        const int cur_r  = base + cur_rb;
        const int cur_s  = s, cur_e = e;
        const int src_l  = src_next;
        const float4 xv  = xv_next;

        // software pipeline: issue next iteration's index batch + self-read now
        if (it < 7) {
            int nrb = rowbase + (it + 1) * 2 + sw;
            int nr  = base + nrb;
            s = (nr < N) ? seg[nrb] : 0;
            e = (nr < N) ? seg[nrb + 1] : 0;
            src_next = (s + sl < e) ? esrc[s + sl] : 0;
            xv_next = make_float4(0.f, 0.f, 0.f, 0.f);
            if (nr < N) xv_next = *(const float4*)(x + (size_t)nr * FD + 4 * sl);
        }

        if (cur_r < N) {
            float4 a0 = make_float4(0.f,0.f,0.f,0.f), a1 = a0, a2 = a0, a3 = a0;
            int srcv = src_l;
            for (int cs = cur_s; cs < cur_e; cs += 32) {
                int m = cur_e - cs; if (m > 32) m = 32;
                if (cs != cur_s)   // rare: degree > 32
                    srcv = (cs + sl < cur_e) ? esrc[cs + sl] : 0;
                int j = 0;
                for (; j + 4 <= m; j += 4) {
                    int s0 = __shfl(srcv, lb + j);
                    int s1 = __shfl(srcv, lb + j + 1);
                    int s2 = __shfl(srcv, lb + j + 2);
                    int s3 = __shfl(srcv, lb + j + 3);
                    float4 v0 = *(const float4*)(x + (size_t)s0 * FD + 4 * sl);
                    float4 v1 = *(const float4*)(x + (size_t)s1 * FD + 4 * sl);
                    float4 v2 = *(const float4*)(x + (size_t)s2 * FD + 4 * sl);
                    float4 v3 = *(const float4*)(x + (size_t)s3 * FD + 4 * sl);
                    a0.x += v0.x; a0.y += v0.y; a0.z += v0.z; a0.w += v0.w;
                    a1.x += v1.x; a1.y += v1.y; a1.z += v1.z; a1.w += v1.w;
                    a2.x += v2.x; a2.y += v2.y; a2.z += v2.z; a2.w += v2.w;
                    a3.x += v3.x; a3.y += v3.y; a3.z += v3.z; a3.w += v3.w;
                }
                for (; j < m; ++j) {
                    int s0 = __shfl(srcv, lb + j);
                    float4 v0 = *(const float4*)(x + (size_t)s0 * FD + 4 * sl);
                    a0.x += v0.x; a0.y += v0.y; a0.z += v0.z; a0.w += v0.w;
                }
            }
            int deg = cur_e - cur_s;
            float inv = 1.0f / (float)(deg > 0 ? deg : 1);
            float4 h4;
            h4.x = xv.x + (a0.x + a1.x + a2.x + a3.x) * inv;
            h4.y = xv.y + (a0.y + a1.y + a2.y + a3.y) * inv;
            h4.z = xv.z + (a0.z + a1.z + a2.z + a3.z) * inv;
            h4.w = xv.w + (a0.w + a1.w + a2.w + a3.w) * inv;
            *(float4*)(sh + cur_rb * HS + 4 * sl) = h4;
        }
    }
    __syncthreads();

    // ---- Phase 2: GEMM h[64][128] @ W[128][128] + b, ReLU ----
    const int cg = t & 15;   // column group: cols [8cg, 8cg+8)
    const int rg = t >> 4;   // row group: rows [4rg, 4rg+4)

    float acc[4][8];
#pragma unroll
    for (int i = 0; i < 4; ++i)
#pragma unroll
        for (int j = 0; j < 8; ++j) acc[i][j] = 0.f;

#pragma unroll 4
    for (int k = 0; k < FD; ++k) {
        float hv[4];
#pragma unroll
        for (int i = 0; i < 4; ++i) hv[i] = sh[(4 * rg + i) * HS + k];
        float4 w0 = *(const float4*)(W + k * FD + 8 * cg);
        float4 w1 = *(const float4*)(W + k * FD + 8 * cg + 4);
        float wv[8] = {w0.x, w0.y, w0.z, w0.w, w1.x, w1.y, w1.z, w1.w};
#pragma unroll
        for (int i = 0; i < 4; ++i)
#pragma unroll
            for (int j = 0; j < 8; ++j)
                acc[i][j] += hv[i] * wv[j];
    }

    float4 b0 = *(const float4*)(bias + 8 * cg);
    float4 b1 = *(const float4*)(bias + 8 * cg + 4);
    float bv[8] = {b0.x, b0.y, b0.z, b0.w, b1.x, b1.y, b1.z, b1.w};

#pragma unroll
    for (int i = 0; i < 4; ++i) {
        int r2 = base + 4 * rg + i;
        if (r2 >= N) continue;
        float o[8];
#pragma unroll
        for (int j = 0; j < 8; ++j) {
            float v = acc[i][j] + bv[j];
            o[j] = v > 0.f ? v : 0.f;
        }
        *(float4*)(out + (size_t)r2 * FD + 8 * cg) = make_float4(o[0], o[1], o[2], o[3]);
        *(float4*)(out + (size_t)r2 * FD + 8 * cg + 4) = make_float4(o[4], o[5], o[6], o[7]);
    }
}

extern "C" void kernel_launch(void* const* d_in, const int* in_sizes, int n_in,
                              void* d_out, int out_size, void* d_ws, size_t ws_size,
                              hipStream_t stream) {
    const float* x    = (const float*)d_in[0];
    const float* W    = (const float*)d_in[1];
    const float* bias = (const float*)d_in[2];
    const int* esrc   = (const int*)d_in[3];
    const int* edst   = (const int*)d_in[4];
    float* out        = (float*)d_out;

    int N = in_sizes[0] / FD;
    int E = in_sizes[3];

    int blocks = (N + BR - 1) / BR;
    meanagg_fused_kernel<<<blocks, 256, 0, stream>>>(x, W, bias, esrc, edst, out, N, E);
}

// Round 6
// 76.942 us; speedup vs baseline: 2.5145x; 1.4898x over previous
//
#include <hip/hip_runtime.h>
#include <hip/hip_bf16.h>

// Fused: segment-mean neighbor aggregation (COO, sorted dst) + x + mean,
// then [64x128] @ W[128x128] + b, ReLU, fp32 out.
//
// Block = 256 threads (4 waves), BR=64 rows.
// Phase 0: 65 parallel binary searches for segment bounds (edge_dst sorted).
// Phase 1: half-wave (32 lanes) per row, float4/lane, 8-deep predicated
//   gather batches (deg<=8 rows pay ONE memory latency), dummy lanes clamp
//   to x-row-0 (L1-hot). Next row's esrc batch + self-read pipelined ahead.
//   h converted to bf16 and written to LDS (stride 136: MFMA ds_read_b128
//   conflict-free).
// Phase 2: bf16 MFMA GEMM (16x16x32): wave w owns cols [32w,32w+32),
//   4 row-tiles x 2 col-tiles x 4 k-steps; W fragments from global (L2-hot).

#define FD  128    // feature dim == out dim
#define BR  64     // rows per block
#define HSB 136    // LDS h row stride in bf16 elems (272 B)

typedef __attribute__((ext_vector_type(8))) short bf16x8;
typedef __attribute__((ext_vector_type(4))) float f32x4;

__device__ __forceinline__ short f2bf(float f) {
    unsigned u = __float_as_uint(f);
    unsigned r = (u + 0x7FFFu + ((u >> 16) & 1u)) >> 16;   // RNE
    return (short)r;
}

__global__ __launch_bounds__(256) void meanagg_fused_kernel(
    const float* __restrict__ x, const float* __restrict__ W,
    const float* __restrict__ bias, const int* __restrict__ esrc,
    const int* __restrict__ edst, float* __restrict__ out, int N, int E)
{
    __shared__ short shb[BR * HSB];   // 17408 B
    __shared__ int seg[BR + 1];

    const int t = threadIdx.x;
    const int base = blockIdx.x * BR;

    // ---- Phase 0: segment boundaries via lower_bound on sorted edge_dst ----
    if (t < BR + 1) {
        int v = base + t;
        int lo = 0, hi = E;
        while (lo < hi) {
            int mid = (lo + hi) >> 1;
            if (edst[mid] < v) lo = mid + 1; else hi = mid;
        }
        seg[t] = lo;
    }
    __syncthreads();

    // ---- Phase 1: h = x + segment_mean(x[src]) -> bf16 LDS ----
    const int wave = t >> 6;
    const int lane = t & 63;
    const int sw = lane >> 5;      // subwave (row within pair)
    const int sl = lane & 31;      // sublane: owns features [4sl, 4sl+4)
    const int lb = sw << 5;        // shfl lane base for this subwave
    const int rowbase = wave * 16;

    // prologue: prefetch iteration 0
    {
        int rb0 = rowbase + sw;
        int r0  = base + rb0;
        int s0  = (r0 < N) ? seg[rb0] : 0;
        int e0  = (r0 < N) ? seg[rb0 + 1] : 0;
        int src_next = (s0 + sl < e0) ? esrc[s0 + sl] : 0;
        float4 xv_next = make_float4(0.f, 0.f, 0.f, 0.f);
        if (r0 < N) xv_next = *(const float4*)(x + (size_t)r0 * FD + 4 * sl);

        int s = s0, e = e0;
        for (int it = 0; it < 8; ++it) {
            const int cur_rb = rowbase + it * 2 + sw;
            const int cur_r  = base + cur_rb;
            const int cur_s  = s, cur_e = e;
            const int src_l  = src_next;
            const float4 xv  = xv_next;

            // software pipeline: issue next iteration's index batch + self-read
            if (it < 7) {
                int nrb = rowbase + (it + 1) * 2 + sw;
                int nr  = base + nrb;
                s = (nr < N) ? seg[nrb] : 0;
                e = (nr < N) ? seg[nrb + 1] : 0;
                src_next = (s + sl < e) ? esrc[s + sl] : 0;
                xv_next = make_float4(0.f, 0.f, 0.f, 0.f);
                if (nr < N) xv_next = *(const float4*)(x + (size_t)nr * FD + 4 * sl);
            }

            if (cur_r < N) {
                float4 a0 = make_float4(0.f, 0.f, 0.f, 0.f), a1 = a0;
                int srcv = src_l;
                for (int cs = cur_s; cs < cur_e; cs += 32) {
                    int m = cur_e - cs; if (m > 32) m = 32;
                    if (cs != cur_s)   // rare: degree > 32
                        srcv = (cs + sl < cur_e) ? esrc[cs + sl] : 0;
                    for (int j0 = 0; j0 < m; j0 += 8) {
                        const int rem = m - j0;
                        float4 v[8];
#pragma unroll
                        for (int u = 0; u < 8; ++u) {
                            int idx = __shfl(srcv, lb + ((j0 + u) & 31)); // clamped lanes carry 0
                            v[u] = *(const float4*)(x + (size_t)idx * FD + 4 * sl);
                        }
#pragma unroll
                        for (int u = 0; u < 8; ++u) {
                            float f = (u < rem) ? 1.f : 0.f;
                            float4* A = (u & 1) ? &a1 : &a0;
                            A->x = fmaf(v[u].x, f, A->x);
                            A->y = fmaf(v[u].y, f, A->y);
                            A->z = fmaf(v[u].z, f, A->z);
                            A->w = fmaf(v[u].w, f, A->w);
                        }
                    }
                }
                int deg = cur_e - cur_s;
                float inv = 1.0f / (float)(deg > 0 ? deg : 1);
                union { short4 s4; } hb;
                hb.s4.x = f2bf(xv.x + (a0.x + a1.x) * inv);
                hb.s4.y = f2bf(xv.y + (a0.y + a1.y) * inv);
                hb.s4.z = f2bf(xv.z + (a0.z + a1.z) * inv);
                hb.s4.w = f2bf(xv.w + (a0.w + a1.w) * inv);
                *(short4*)(shb + cur_rb * HSB + 4 * sl) = hb.s4;   // 8B, 2-way max (free)
            }
        }
    }
    __syncthreads();

    // ---- Phase 2: bf16 MFMA GEMM h[64][128] @ W[128][128] + b, ReLU ----
    const int lr = lane & 15;      // row-in-tile (A) / col-in-tile (B,C)
    const int q  = lane >> 4;      // k-quarter (A,B) / row-quarter (C)
    const int colb = wave * 32;

    // B fragments: lane holds W[kt*32 + q*8 + e][colb + ct*16 + lr], e=0..7
    bf16x8 bfr[2][4];
#pragma unroll
    for (int ct = 0; ct < 2; ++ct) {
        int col = colb + ct * 16 + lr;
#pragma unroll
        for (int kt = 0; kt < 4; ++kt) {
            bf16x8 f;
#pragma unroll
            for (int e = 0; e < 8; ++e)
                f[e] = f2bf(W[(size_t)(kt * 32 + q * 8 + e) * FD + col]);
            bfr[ct][kt] = f;
        }
    }

    f32x4 acc[4][2];
#pragma unroll
    for (int rt = 0; rt < 4; ++rt) {
        acc[rt][0] = (f32x4){0.f, 0.f, 0.f, 0.f};
        acc[rt][1] = (f32x4){0.f, 0.f, 0.f, 0.f};
    }

#pragma unroll
    for (int rt = 0; rt < 4; ++rt) {
#pragma unroll
        for (int kt = 0; kt < 4; ++kt) {
            bf16x8 a = *(const bf16x8*)(shb + (rt * 16 + lr) * HSB + kt * 32 + q * 8);
            acc[rt][0] = __builtin_amdgcn_mfma_f32_16x16x32_bf16(a, bfr[0][kt], acc[rt][0], 0, 0, 0);
            acc[rt][1] = __builtin_amdgcn_mfma_f32_16x16x32_bf16(a, bfr[1][kt], acc[rt][1], 0, 0, 0);
        }
    }

    const float b0 = bias[colb + lr];
    const float b1 = bias[colb + 16 + lr];

#pragma unroll
    for (int rt = 0; rt < 4; ++rt) {
#pragma unroll
        for (int j = 0; j < 4; ++j) {
            int row = base + rt * 16 + q * 4 + j;
            if (row < N) {
                float v0 = acc[rt][0][j] + b0; v0 = v0 > 0.f ? v0 : 0.f;
                float v1 = acc[rt][1][j] + b1; v1 = v1 > 0.f ? v1 : 0.f;
                out[(size_t)row * FD + colb + lr]      = v0;
                out[(size_t)row * FD + colb + 16 + lr] = v1;
            }
        }
    }
}

extern "C" void kernel_launch(void* const* d_in, const int* in_sizes, int n_in,
                              void* d_out, int out_size, void* d_ws, size_t ws_size,
                              hipStream_t stream) {
    const float* x    = (const float*)d_in[0];
    const float* W    = (const float*)d_in[1];
    const float* bias = (const float*)d_in[2];
    const int* esrc   = (const int*)d_in[3];
    const int* edst   = (const int*)d_in[4];
    float* out        = (float*)d_out;

    int N = in_sizes[0] / FD;
    int E = in_sizes[3];

    int blocks = (N + BR - 1) / BR;
    meanagg_fused_kernel<<<blocks, 256, 0, stream>>>(x, W, bias, esrc, edst, out, N, E);
}

// Round 7
// 71.758 us; speedup vs baseline: 2.6961x; 1.0722x over previous
//
#include <hip/hip_runtime.h>
#include <hip/hip_bf16.h>

// Fused GNN layer: h = x + segment_mean(x[edge_src] by edge_dst); out = relu(h@W + b)
//
// Kernel 1 (prep, into d_ws):
//   - row_ptr[N+1] built from sorted edge_dst via boundary scatter (1 thread/edge)
//   - W prepacked to bf16 in MFMA B-fragment order (32 KB)
// Kernel 2 (main): BR=64 rows/block, 256 threads.
//   Phase 0: seg[] <- row_ptr (ONE coalesced load; binary search eliminated)
//   Phase 1: half-wave per row, float4/lane, 8-deep predicated gather batches.
//   Phase 2: bf16 MFMA 16x16x32; B fragments = 8x16B loads from packed W.
// Fallback (ws too small): round-6 self-contained kernel with binary search.

#define FD  128
#define BR  64
#define HSB 136    // LDS h row stride in bf16 elems

typedef __attribute__((ext_vector_type(8))) short bf16x8;
typedef __attribute__((ext_vector_type(4))) float f32x4;

__device__ __forceinline__ short f2bf(float f) {
    unsigned u = __float_as_uint(f);
    unsigned r = (u + 0x7FFFu + ((u >> 16) & 1u)) >> 16;   // RNE
    return (short)r;
}

// ---------------- prep kernel ----------------
__global__ __launch_bounds__(256) void prep_kernel(
    const float* __restrict__ W, const int* __restrict__ edst,
    int* __restrict__ rp, short* __restrict__ pkW, int N, int E)
{
    int gid = blockIdx.x * 256 + threadIdx.x;
    if (gid < E) {
        int cur = edst[gid];
        int prev = gid ? edst[gid - 1] : -1;
        for (int v = prev + 1; v <= cur; ++v) rp[v] = gid;
        if (gid == E - 1)
            for (int v = cur + 1; v <= N; ++v) rp[v] = E;
    }
    // W prepack: frag f -> (wave, ct, kt, lane); lane = q*16+lr
    // pkW[f*8+e] = bf16(W[(kt*32 + q*8 + e)*FD + wave*32 + ct*16 + lr])
    if (gid < 2048) {
        int wave = gid >> 9, rem = gid & 511;
        int ct = rem >> 8, rem2 = rem & 255;
        int kt = rem2 >> 6, lane = rem2 & 63;
        int q = lane >> 4, lr = lane & 15;
        int col = wave * 32 + ct * 16 + lr;
        int k0 = kt * 32 + q * 8;
        short tmp[8];
#pragma unroll
        for (int e = 0; e < 8; ++e)
            tmp[e] = f2bf(W[(size_t)(k0 + e) * FD + col]);
        *(bf16x8*)(pkW + (size_t)gid * 8) = *(bf16x8*)tmp;
    }
}

// ---------------- main kernel (rp + packed W) ----------------
__global__ __launch_bounds__(256) void meanagg_main_kernel(
    const float* __restrict__ x, const short* __restrict__ pkW,
    const float* __restrict__ bias, const int* __restrict__ esrc,
    const int* __restrict__ rp, float* __restrict__ out, int N, int E)
{
    __shared__ short shb[BR * HSB];
    __shared__ int seg[BR + 1];

    const int t = threadIdx.x;
    const int base = blockIdx.x * BR;

    if (t < BR + 1) {
        int idx = base + t;
        seg[t] = rp[idx > N ? N : idx];
    }
    __syncthreads();

    const int wave = t >> 6;
    const int lane = t & 63;
    const int sw = lane >> 5;
    const int sl = lane & 31;
    const int lb = sw << 5;
    const int rowbase = wave * 16;

    {
        int rb0 = rowbase + sw;
        int r0  = base + rb0;
        int s0  = (r0 < N) ? seg[rb0] : 0;
        int e0  = (r0 < N) ? seg[rb0 + 1] : 0;
        int src_next = (s0 + sl < e0) ? esrc[s0 + sl] : 0;
        float4 xv_next = make_float4(0.f, 0.f, 0.f, 0.f);
        if (r0 < N) xv_next = *(const float4*)(x + (size_t)r0 * FD + 4 * sl);

        int s = s0, e = e0;
        for (int it = 0; it < 8; ++it) {
            const int cur_rb = rowbase + it * 2 + sw;
            const int cur_r  = base + cur_rb;
            const int cur_s  = s, cur_e = e;
            const int src_l  = src_next;
            const float4 xv  = xv_next;

            if (it < 7) {
                int nrb = rowbase + (it + 1) * 2 + sw;
                int nr  = base + nrb;
                s = (nr < N) ? seg[nrb] : 0;
                e = (nr < N) ? seg[nrb + 1] : 0;
                src_next = (s + sl < e) ? esrc[s + sl] : 0;
                xv_next = make_float4(0.f, 0.f, 0.f, 0.f);
                if (nr < N) xv_next = *(const float4*)(x + (size_t)nr * FD + 4 * sl);
            }

            if (cur_r < N) {
                float4 a0 = make_float4(0.f, 0.f, 0.f, 0.f), a1 = a0;
                int srcv = src_l;
                for (int cs = cur_s; cs < cur_e; cs += 32) {
                    int m = cur_e - cs; if (m > 32) m = 32;
                    if (cs != cur_s)
                        srcv = (cs + sl < cur_e) ? esrc[cs + sl] : 0;
                    for (int j0 = 0; j0 < m; j0 += 8) {
                        const int rem = m - j0;
                        float4 v[8];
#pragma unroll
                        for (int u = 0; u < 8; ++u) {
                            int idx = __shfl(srcv, lb + ((j0 + u) & 31));
                            v[u] = *(const float4*)(x + (size_t)idx * FD + 4 * sl);
                        }
#pragma unroll
                        for (int u = 0; u < 8; ++u) {
                            float f = (u < rem) ? 1.f : 0.f;
                            float4* A = (u & 1) ? &a1 : &a0;
                            A->x = fmaf(v[u].x, f, A->x);
                            A->y = fmaf(v[u].y, f, A->y);
                            A->z = fmaf(v[u].z, f, A->z);
                            A->w = fmaf(v[u].w, f, A->w);
                        }
                    }
                }
                int deg = cur_e - cur_s;
                float inv = 1.0f / (float)(deg > 0 ? deg : 1);
                short4 hb;
                hb.x = f2bf(xv.x + (a0.x + a1.x) * inv);
                hb.y = f2bf(xv.y + (a0.y + a1.y) * inv);
                hb.z = f2bf(xv.z + (a0.z + a1.z) * inv);
                hb.w = f2bf(xv.w + (a0.w + a1.w) * inv);
                *(short4*)(shb + cur_rb * HSB + 4 * sl) = hb;
            }
        }
    }
    __syncthreads();

    // Phase 2: bf16 MFMA
    const int lr = lane & 15;
    const int q  = lane >> 4;
    const int colb = wave * 32;

    bf16x8 bfr[2][4];
#pragma unroll
    for (int ct = 0; ct < 2; ++ct)
#pragma unroll
        for (int kt = 0; kt < 4; ++kt) {
            int f = ((wave * 2 + ct) * 4 + kt) * 64 + lane;
            bfr[ct][kt] = *(const bf16x8*)(pkW + (size_t)f * 8);
        }

    f32x4 acc[4][2];
#pragma unroll
    for (int rt = 0; rt < 4; ++rt) {
        acc[rt][0] = (f32x4){0.f, 0.f, 0.f, 0.f};
        acc[rt][1] = (f32x4){0.f, 0.f, 0.f, 0.f};
    }

#pragma unroll
    for (int rt = 0; rt < 4; ++rt)
#pragma unroll
        for (int kt = 0; kt < 4; ++kt) {
            bf16x8 a = *(const bf16x8*)(shb + (rt * 16 + lr) * HSB + kt * 32 + q * 8);
            acc[rt][0] = __builtin_amdgcn_mfma_f32_16x16x32_bf16(a, bfr[0][kt], acc[rt][0], 0, 0, 0);
            acc[rt][1] = __builtin_amdgcn_mfma_f32_16x16x32_bf16(a, bfr[1][kt], acc[rt][1], 0, 0, 0);
        }

    const float b0 = bias[colb + lr];
    const float b1 = bias[colb + 16 + lr];

#pragma unroll
    for (int rt = 0; rt < 4; ++rt)
#pragma unroll
        for (int j = 0; j < 4; ++j) {
            int row = base + rt * 16 + q * 4 + j;
            if (row < N) {
                float v0 = acc[rt][0][j] + b0; v0 = v0 > 0.f ? v0 : 0.f;
                float v1 = acc[rt][1][j] + b1; v1 = v1 > 0.f ? v1 : 0.f;
                out[(size_t)row * FD + colb + lr]      = v0;
                out[(size_t)row * FD + colb + 16 + lr] = v1;
            }
        }
}

// ---------------- fallback kernel (round-6, self-contained) ----------------
__global__ __launch_bounds__(256) void meanagg_fused_kernel(
    const float* __restrict__ x, const float* __restrict__ W,
    const float* __restrict__ bias, const int* __restrict__ esrc,
    const int* __restrict__ edst, float* __restrict__ out, int N, int E)
{
    __shared__ short shb[BR * HSB];
    __shared__ int seg[BR + 1];

    const int t = threadIdx.x;
    const int base = blockIdx.x * BR;

    if (t < BR + 1) {
        int v = base + t;
        int lo = 0, hi = E;
        while (lo < hi) {
            int mid = (lo + hi) >> 1;
            if (edst[mid] < v) lo = mid + 1; else hi = mid;
        }
        seg[t] = lo;
    }
    __syncthreads();

    const int wave = t >> 6;
    const int lane = t & 63;
    const int sw = lane >> 5;
    const int sl = lane & 31;
    const int lb = sw << 5;
    const int rowbase = wave * 16;

    {
        int rb0 = rowbase + sw;
        int r0  = base + rb0;
        int s0  = (r0 < N) ? seg[rb0] : 0;
        int e0  = (r0 < N) ? seg[rb0 + 1] : 0;
        int src_next = (s0 + sl < e0) ? esrc[s0 + sl] : 0;
        float4 xv_next = make_float4(0.f, 0.f, 0.f, 0.f);
        if (r0 < N) xv_next = *(const float4*)(x + (size_t)r0 * FD + 4 * sl);

        int s = s0, e = e0;
        for (int it = 0; it < 8; ++it) {
            const int cur_rb = rowbase + it * 2 + sw;
            const int cur_r  = base + cur_rb;
            const int cur_s  = s, cur_e = e;
            const int src_l  = src_next;
            const float4 xv  = xv_next;

            if (it < 7) {
                int nrb = rowbase + (it + 1) * 2 + sw;
                int nr  = base + nrb;
                s = (nr < N) ? seg[nrb] : 0;
                e = (nr < N) ? seg[nrb + 1] : 0;
                src_next = (s + sl < e) ? esrc[s + sl] : 0;
                xv_next = make_float4(0.f, 0.f, 0.f, 0.f);
                if (nr < N) xv_next = *(const float4*)(x + (size_t)nr * FD + 4 * sl);
            }

            if (cur_r < N) {
                float4 a0 = make_float4(0.f, 0.f, 0.f, 0.f), a1 = a0;
                int srcv = src_l;
                for (int cs = cur_s; cs < cur_e; cs += 32) {
                    int m = cur_e - cs; if (m > 32) m = 32;
                    if (cs != cur_s)
                        srcv = (cs + sl < cur_e) ? esrc[cs + sl] : 0;
                    for (int j0 = 0; j0 < m; j0 += 8) {
                        const int rem = m - j0;
                        float4 v[8];
#pragma unroll
                        for (int u = 0; u < 8; ++u) {
                            int idx = __shfl(srcv, lb + ((j0 + u) & 31));
                            v[u] = *(const float4*)(x + (size_t)idx * FD + 4 * sl);
                        }
#pragma unroll
                        for (int u = 0; u < 8; ++u) {
                            float f = (u < rem) ? 1.f : 0.f;
                            float4* A = (u & 1) ? &a1 : &a0;
                            A->x = fmaf(v[u].x, f, A->x);
                            A->y = fmaf(v[u].y, f, A->y);
                            A->z = fmaf(v[u].z, f, A->z);
                            A->w = fmaf(v[u].w, f, A->w);
                        }
                    }
                }
                int deg = cur_e - cur_s;
                float inv = 1.0f / (float)(deg > 0 ? deg : 1);
                short4 hb;
                hb.x = f2bf(xv.x + (a0.x + a1.x) * inv);
                hb.y = f2bf(xv.y + (a0.y + a1.y) * inv);
                hb.z = f2bf(xv.z + (a0.z + a1.z) * inv);
                hb.w = f2bf(xv.w + (a0.w + a1.w) * inv);
                *(short4*)(shb + cur_rb * HSB + 4 * sl) = hb;
            }
        }
    }
    __syncthreads();

    const int lr = lane & 15;
    const int q  = lane >> 4;
    const int colb = wave * 32;

    bf16x8 bfr[2][4];
#pragma unroll
    for (int ct = 0; ct < 2; ++ct) {
        int col = colb + ct * 16 + lr;
#pragma unroll
        for (int kt = 0; kt < 4; ++kt) {
            bf16x8 f;
#pragma unroll
            for (int e = 0; e < 8; ++e)
                f[e] = f2bf(W[(size_t)(kt * 32 + q * 8 + e) * FD + col]);
            bfr[ct][kt] = f;
        }
    }

    f32x4 acc[4][2];
#pragma unroll
    for (int rt = 0; rt < 4; ++rt) {
        acc[rt][0] = (f32x4){0.f, 0.f, 0.f, 0.f};
        acc[rt][1] = (f32x4){0.f, 0.f, 0.f, 0.f};
    }

#pragma unroll
    for (int rt = 0; rt < 4; ++rt)
#pragma unroll
        for (int kt = 0; kt < 4; ++kt) {
            bf16x8 a = *(const bf16x8*)(shb + (rt * 16 + lr) * HSB + kt * 32 + q * 8);
            acc[rt][0] = __builtin_amdgcn_mfma_f32_16x16x32_bf16(a, bfr[0][kt], acc[rt][0], 0, 0, 0);
            acc[rt][1] = __builtin_amdgcn_mfma_f32_16x16x32_bf16(a, bfr[1][kt], acc[rt][1], 0, 0, 0);
        }

    const float b0 = bias[colb + lr];
    const float b1 = bias[colb + 16 + lr];

#pragma unroll
    for (int rt = 0; rt < 4; ++rt)
#pragma unroll
        for (int j = 0; j < 4; ++j) {
            int row = base + rt * 16 + q * 4 + j;
            if (row < N) {
                float v0 = acc[rt][0][j] + b0; v0 = v0 > 0.f ? v0 : 0.f;
                float v1 = acc[rt][1][j] + b1; v1 = v1 > 0.f ? v1 : 0.f;
                out[(size_t)row * FD + colb + lr]      = v0;
                out[(size_t)row * FD + colb + 16 + lr] = v1;
            }
        }
}

extern "C" void kernel_launch(void* const* d_in, const int* in_sizes, int n_in,
                              void* d_out, int out_size, void* d_ws, size_t ws_size,
                              hipStream_t stream) {
    const float* x    = (const float*)d_in[0];
    const float* W    = (const float*)d_in[1];
    const float* bias = (const float*)d_in[2];
    const int* esrc   = (const int*)d_in[3];
    const int* edst   = (const int*)d_in[4];
    float* out        = (float*)d_out;

    int N = in_sizes[0] / FD;
    int E = in_sizes[3];
    int blocks = (N + BR - 1) / BR;

    size_t rp_bytes  = (size_t)(N + 1) * 4;
    size_t pk_off    = (rp_bytes + 511) & ~(size_t)511;
    size_t need      = pk_off + 2048 * 8 * 2;   // packed W: 32 KB

    if (ws_size >= need) {
        int* rp    = (int*)d_ws;
        short* pkW = (short*)((char*)d_ws + pk_off);
        int pblocks = (E + 255) / 256;
        prep_kernel<<<pblocks, 256, 0, stream>>>(W, edst, rp, pkW, N, E);
        meanagg_main_kernel<<<blocks, 256, 0, stream>>>(x, pkW, bias, esrc, rp, out, N, E);
    } else {
        meanagg_fused_kernel<<<blocks, 256, 0, stream>>>(x, W, bias, esrc, edst, out, N, E);
    }
}

// Round 8
// 57.645 us; speedup vs baseline: 3.3562x; 1.2448x over previous
//
#include <hip/hip_runtime.h>
#include <hip/hip_bf16.h>

// Fused GNN layer: h = x + segment_mean(x[edge_src] by edge_dst); out = relu(h@W + b)
//
// Full path (ws >= ~26.5 MB):
//   prep_full: row_ptr scatter + W bf16 MFMA-fragment pack + x -> bf16 (xb)
//   main2: BR=64/block; quarter-wave (16 lanes) per row => 4 rows in flight
//          per wave, bf16 gathers (256 B/row), 6-deep predicated batches;
//          bf16 MFMA 16x16x32 GEMM with packed W.
// Medium path (ws >= ~433 KB): round-7 kernels (fp32 gather, rp + pkW).
// Small path: round-6 self-contained kernel (binary search + inline W pack).

#define FD  128
#define BR  64
#define HSB 136    // LDS h row stride in bf16 elems

typedef __attribute__((ext_vector_type(8))) short bf16x8;
typedef __attribute__((ext_vector_type(4))) float f32x4;

__device__ __forceinline__ short f2bf(float f) {
    unsigned u = __float_as_uint(f);
    return (short)((u + 0x7FFFu + ((u >> 16) & 1u)) >> 16);   // RNE
}
__device__ __forceinline__ float bf2f(short s) {
    return __uint_as_float(((unsigned)(unsigned short)s) << 16);
}

// ---------------- prep (full): rp + packed W + x->bf16 ----------------
__global__ __launch_bounds__(256) void prep_full_kernel(
    const float* __restrict__ x, const float* __restrict__ W,
    const int* __restrict__ edst, int* __restrict__ rp,
    short* __restrict__ pkW, short* __restrict__ xb, int N, int E)
{
    const int gid = blockIdx.x * 256 + threadIdx.x;
    const int nth = gridDim.x * 256;

    // x -> bf16, 8 elems/thread, grid-stride
    const int nv = N * FD / 8;
    for (int i = gid; i < nv; i += nth) {
        float4 f0 = *(const float4*)(x + (size_t)i * 8);
        float4 f1 = *(const float4*)(x + (size_t)i * 8 + 4);
        short tmp[8] = {f2bf(f0.x), f2bf(f0.y), f2bf(f0.z), f2bf(f0.w),
                        f2bf(f1.x), f2bf(f1.y), f2bf(f1.z), f2bf(f1.w)};
        *(bf16x8*)(xb + (size_t)i * 8) = *(bf16x8*)tmp;
    }
    // row_ptr scatter (edge_dst sorted)
    for (int e = gid; e < E; e += nth) {
        int cur = edst[e];
        int prev = e ? edst[e - 1] : -1;
        for (int v = prev + 1; v <= cur; ++v) rp[v] = e;
        if (e == E - 1)
            for (int v = cur + 1; v <= N; ++v) rp[v] = E;
    }
    // W pack: f = wave*512 + ct*256 + kt*64 + lane; lane = q*16+lr
    if (gid < 2048) {
        int wave = gid >> 9, rem = gid & 511;
        int ct = rem >> 8, rem2 = rem & 255;
        int kt = rem2 >> 6, lane = rem2 & 63;
        int q = lane >> 4, lr = lane & 15;
        int col = wave * 32 + ct * 16 + lr;
        int k0 = kt * 32 + q * 8;
        short tmp[8];
#pragma unroll
        for (int e2 = 0; e2 < 8; ++e2)
            tmp[e2] = f2bf(W[(size_t)(k0 + e2) * FD + col]);
        *(bf16x8*)(pkW + (size_t)gid * 8) = *(bf16x8*)tmp;
    }
}

// ---------------- main2: bf16 gather, quarter-wave per row ----------------
__global__ __launch_bounds__(256) void meanagg_main2_kernel(
    const short* __restrict__ xb, const short* __restrict__ pkW,
    const float* __restrict__ bias, const int* __restrict__ esrc,
    const int* __restrict__ rp, float* __restrict__ out, int N, int E)
{
    __shared__ short shb[BR * HSB];
    __shared__ int seg[BR + 1];

    const int t = threadIdx.x;
    const int base = blockIdx.x * BR;

    if (t < BR + 1) {
        int idx = base + t;
        seg[t] = rp[idx > N ? N : idx];
    }
    __syncthreads();

    const int wave = t >> 6;
    const int lane = t & 63;
    const int qw = lane >> 4;      // quarter-wave: row within group of 4
    const int ql = lane & 15;      // sublane: owns features [8ql, 8ql+8)
    const int qb = qw << 4;        // shfl lane base
    const int rowbase = wave * 16;

    {
        // prologue: prefetch it=0
        int rb0 = rowbase + qw;
        int r0  = base + rb0;
        int s = (r0 < N) ? seg[rb0] : 0;
        int e = (r0 < N) ? seg[rb0 + 1] : 0;
        int srcv_n = (s + ql < e) ? esrc[s + ql] : 0;
        bf16x8 xv_n = {0, 0, 0, 0, 0, 0, 0, 0};
        if (r0 < N) xv_n = *(const bf16x8*)(xb + (size_t)r0 * FD + 8 * ql);

        for (int it = 0; it < 4; ++it) {
            const int cur_rb = rowbase + it * 4 + qw;
            const int cur_r  = base + cur_rb;
            const int cs0 = s, ce = e;
            int srcv = srcv_n;
            const bf16x8 xv = xv_n;

            // prefetch next iteration (indices + self row)
            if (it < 3) {
                int nrb = rowbase + (it + 1) * 4 + qw;
                int nr  = base + nrb;
                s = (nr < N) ? seg[nrb] : 0;
                e = (nr < N) ? seg[nrb + 1] : 0;
                srcv_n = (s + ql < e) ? esrc[s + ql] : 0;
                bf16x8 z = {0, 0, 0, 0, 0, 0, 0, 0};
                xv_n = z;
                if (nr < N) xv_n = *(const bf16x8*)(xb + (size_t)nr * FD + 8 * ql);
            }

            if (cur_r < N) {
                float a[8];
#pragma unroll
                for (int p = 0; p < 8; ++p) a[p] = 0.f;

                for (int cs = cs0; cs < ce; cs += 16) {
                    int m = ce - cs; if (m > 16) m = 16;
                    if (cs != cs0)   // deg > 16: reload index batch
                        srcv = (cs + ql < ce) ? esrc[cs + ql] : 0;
                    for (int j0 = 0; j0 < m; j0 += 6) {
                        uint4 v[6];
#pragma unroll
                        for (int u = 0; u < 6; ++u) {
                            int jj = j0 + u;
                            int idx = __shfl(srcv, qb + (jj & 15));
                            if (jj >= m) idx = 0;   // dummy -> hot row 0
                            v[u] = *(const uint4*)(xb + (size_t)idx * FD + 8 * ql);
                        }
#pragma unroll
                        for (int u = 0; u < 6; ++u) {
                            float f = (j0 + u < m) ? 1.f : 0.f;
                            unsigned w;
                            w = v[u].x;
                            a[0] = fmaf(__uint_as_float(w << 16), f, a[0]);
                            a[1] = fmaf(__uint_as_float(w & 0xFFFF0000u), f, a[1]);
                            w = v[u].y;
                            a[2] = fmaf(__uint_as_float(w << 16), f, a[2]);
                            a[3] = fmaf(__uint_as_float(w & 0xFFFF0000u), f, a[3]);
                            w = v[u].z;
                            a[4] = fmaf(__uint_as_float(w << 16), f, a[4]);
                            a[5] = fmaf(__uint_as_float(w & 0xFFFF0000u), f, a[5]);
                            w = v[u].w;
                            a[6] = fmaf(__uint_as_float(w << 16), f, a[6]);
                            a[7] = fmaf(__uint_as_float(w & 0xFFFF0000u), f, a[7]);
                        }
                    }
                }
                int deg = ce - cs0;
                float inv = 1.0f / (float)(deg > 0 ? deg : 1);
                short hb[8];
#pragma unroll
                for (int p = 0; p < 8; ++p)
                    hb[p] = f2bf(bf2f(xv[p]) + a[p] * inv);
                *(bf16x8*)(shb + cur_rb * HSB + 8 * ql) = *(bf16x8*)hb;
            }
        }
    }
    __syncthreads();

    // Phase 2: bf16 MFMA GEMM
    const int lr = lane & 15;
    const int q  = lane >> 4;
    const int colb = wave * 32;

    bf16x8 bfr[2][4];
#pragma unroll
    for (int ct = 0; ct < 2; ++ct)
#pragma unroll
        for (int kt = 0; kt < 4; ++kt) {
            int f = ((wave * 2 + ct) * 4 + kt) * 64 + lane;
            bfr[ct][kt] = *(const bf16x8*)(pkW + (size_t)f * 8);
        }

    f32x4 acc[4][2];
#pragma unroll
    for (int rt = 0; rt < 4; ++rt) {
        acc[rt][0] = (f32x4){0.f, 0.f, 0.f, 0.f};
        acc[rt][1] = (f32x4){0.f, 0.f, 0.f, 0.f};
    }

#pragma unroll
    for (int rt = 0; rt < 4; ++rt)
#pragma unroll
        for (int kt = 0; kt < 4; ++kt) {
            bf16x8 av = *(const bf16x8*)(shb + (rt * 16 + lr) * HSB + kt * 32 + q * 8);
            acc[rt][0] = __builtin_amdgcn_mfma_f32_16x16x32_bf16(av, bfr[0][kt], acc[rt][0], 0, 0, 0);
            acc[rt][1] = __builtin_amdgcn_mfma_f32_16x16x32_bf16(av, bfr[1][kt], acc[rt][1], 0, 0, 0);
        }

    const float b0 = bias[colb + lr];
    const float b1 = bias[colb + 16 + lr];

#pragma unroll
    for (int rt = 0; rt < 4; ++rt)
#pragma unroll
        for (int j = 0; j < 4; ++j) {
            int row = base + rt * 16 + q * 4 + j;
            if (row < N) {
                float v0 = acc[rt][0][j] + b0; v0 = v0 > 0.f ? v0 : 0.f;
                float v1 = acc[rt][1][j] + b1; v1 = v1 > 0.f ? v1 : 0.f;
                out[(size_t)row * FD + colb + lr]      = v0;
                out[(size_t)row * FD + colb + 16 + lr] = v1;
            }
        }
}

// ---------------- medium path: round-7 prep + main (fp32 gather) ----------------
__global__ __launch_bounds__(256) void prep_kernel(
    const float* __restrict__ W, const int* __restrict__ edst,
    int* __restrict__ rp, short* __restrict__ pkW, int N, int E)
{
    int gid = blockIdx.x * 256 + threadIdx.x;
    if (gid < E) {
        int cur = edst[gid];
        int prev = gid ? edst[gid - 1] : -1;
        for (int v = prev + 1; v <= cur; ++v) rp[v] = gid;
        if (gid == E - 1)
            for (int v = cur + 1; v <= N; ++v) rp[v] = E;
    }
    if (gid < 2048) {
        int wave = gid >> 9, rem = gid & 511;
        int ct = rem >> 8, rem2 = rem & 255;
        int kt = rem2 >> 6, lane = rem2 & 63;
        int q = lane >> 4, lr = lane & 15;
        int col = wave * 32 + ct * 16 + lr;
        int k0 = kt * 32 + q * 8;
        short tmp[8];
#pragma unroll
        for (int e = 0; e < 8; ++e)
            tmp[e] = f2bf(W[(size_t)(k0 + e) * FD + col]);
        *(bf16x8*)(pkW + (size_t)gid * 8) = *(bf16x8*)tmp;
    }
}

__global__ __launch_bounds__(256) void meanagg_main_kernel(
    const float* __restrict__ x, const short* __restrict__ pkW,
    const float* __restrict__ bias, const int* __restrict__ esrc,
    const int* __restrict__ rp, float* __restrict__ out, int N, int E)
{
    __shared__ short shb[BR * HSB];
    __shared__ int seg[BR + 1];

    const int t = threadIdx.x;
    const int base = blockIdx.x * BR;

    if (t < BR + 1) {
        int idx = base + t;
        seg[t] = rp[idx > N ? N : idx];
    }
    __syncthreads();

    const int wave = t >> 6;
    const int lane = t & 63;
    const int sw = lane >> 5;
    const int sl = lane & 31;
    const int lb = sw << 5;
    const int rowbase = wave * 16;

    {
        int rb0 = rowbase + sw;
        int r0  = base + rb0;
        int s0  = (r0 < N) ? seg[rb0] : 0;
        int e0  = (r0 < N) ? seg[rb0 + 1] : 0;
        int src_next = (s0 + sl < e0) ? esrc[s0 + sl] : 0;
        float4 xv_next = make_float4(0.f, 0.f, 0.f, 0.f);
        if (r0 < N) xv_next = *(const float4*)(x + (size_t)r0 * FD + 4 * sl);

        int s = s0, e = e0;
        for (int it = 0; it < 8; ++it) {
            const int cur_rb = rowbase + it * 2 + sw;
            const int cur_r  = base + cur_rb;
            const int cur_s  = s, cur_e = e;
            const int src_l  = src_next;
            const float4 xv  = xv_next;

            if (it < 7) {
                int nrb = rowbase + (it + 1) * 2 + sw;
                int nr  = base + nrb;
                s = (nr < N) ? seg[nrb] : 0;
                e = (nr < N) ? seg[nrb + 1] : 0;
                src_next = (s + sl < e) ? esrc[s + sl] : 0;
                xv_next = make_float4(0.f, 0.f, 0.f, 0.f);
                if (nr < N) xv_next = *(const float4*)(x + (size_t)nr * FD + 4 * sl);
            }

            if (cur_r < N) {
                float4 a0 = make_float4(0.f, 0.f, 0.f, 0.f), a1 = a0;
                int srcv = src_l;
                for (int cs = cur_s; cs < cur_e; cs += 32) {
                    int m = cur_e - cs; if (m > 32) m = 32;
                    if (cs != cur_s)
                        srcv = (cs + sl < cur_e) ? esrc[cs + sl] : 0;
                    for (int j0 = 0; j0 < m; j0 += 8) {
                        const int rem = m - j0;
                        float4 v[8];
#pragma unroll
                        for (int u = 0; u < 8; ++u) {
                            int idx = __shfl(srcv, lb + ((j0 + u) & 31));
                            v[u] = *(const float4*)(x + (size_t)idx * FD + 4 * sl);
                        }
#pragma unroll
                        for (int u = 0; u < 8; ++u) {
                            float f = (u < rem) ? 1.f : 0.f;
                            float4* A = (u & 1) ? &a1 : &a0;
                            A->x = fmaf(v[u].x, f, A->x);
                            A->y = fmaf(v[u].y, f, A->y);
                            A->z = fmaf(v[u].z, f, A->z);
                            A->w = fmaf(v[u].w, f, A->w);
                        }
                    }
                }
                int deg = cur_e - cur_s;
                float inv = 1.0f / (float)(deg > 0 ? deg : 1);
                short4 hb;
                hb.x = f2bf(xv.x + (a0.x + a1.x) * inv);
                hb.y = f2bf(xv.y + (a0.y + a1.y) * inv);
                hb.z = f2bf(xv.z + (a0.z + a1.z) * inv);
                hb.w = f2bf(xv.w + (a0.w + a1.w) * inv);
                *(short4*)(shb + cur_rb * HSB + 4 * sl) = hb;
            }
        }
    }
    __syncthreads();

    const int lr = lane & 15;
    const int q  = lane >> 4;
    const int colb = wave * 32;

    bf16x8 bfr[2][4];
#pragma unroll
    for (int ct = 0; ct < 2; ++ct)
#pragma unroll
        for (int kt = 0; kt < 4; ++kt) {
            int f = ((wave * 2 + ct) * 4 + kt) * 64 + lane;
            bfr[ct][kt] = *(const bf16x8*)(pkW + (size_t)f * 8);
        }

    f32x4 acc[4][2];
#pragma unroll
    for (int rt = 0; rt < 4; ++rt) {
        acc[rt][0] = (f32x4){0.f, 0.f, 0.f, 0.f};
        acc[rt][1] = (f32x4){0.f, 0.f, 0.f, 0.f};
    }

#pragma unroll
    for (int rt = 0; rt < 4; ++rt)
#pragma unroll
        for (int kt = 0; kt < 4; ++kt) {
            bf16x8 av = *(const bf16x8*)(shb + (rt * 16 + lr) * HSB + kt * 32 + q * 8);
            acc[rt][0] = __builtin_amdgcn_mfma_f32_16x16x32_bf16(av, bfr[0][kt], acc[rt][0], 0, 0, 0);
            acc[rt][1] = __builtin_amdgcn_mfma_f32_16x16x32_bf16(av, bfr[1][kt], acc[rt][1], 0, 0, 0);
        }

    const float b0 = bias[colb + lr];
    const float b1 = bias[colb + 16 + lr];

#pragma unroll
    for (int rt = 0; rt < 4; ++rt)
#pragma unroll
        for (int j = 0; j < 4; ++j) {
            int row = base + rt * 16 + q * 4 + j;
            if (row < N) {
                float v0 = acc[rt][0][j] + b0; v0 = v0 > 0.f ? v0 : 0.f;
                float v1 = acc[rt][1][j] + b1; v1 = v1 > 0.f ? v1 : 0.f;
                out[(size_t)row * FD + colb + lr]      = v0;
                out[(size_t)row * FD + colb + 16 + lr] = v1;
            }
        }
}

// ---------------- small path: self-contained (round-6) ----------------
__global__ __launch_bounds__(256) void meanagg_fused_kernel(
    const float* __restrict__ x, const float* __restrict__ W,
    const float* __restrict__ bias, const int* __restrict__ esrc,
    const int* __restrict__ edst, float* __restrict__ out, int N, int E)
{
    __shared__ short shb[BR * HSB];
    __shared__ int seg[BR + 1];

    const int t = threadIdx.x;
    const int base = blockIdx.x * BR;

    if (t < BR + 1) {
        int v = base + t;
        int lo = 0, hi = E;
        while (lo < hi) {
            int mid = (lo + hi) >> 1;
            if (edst[mid] < v) lo = mid + 1; else hi = mid;
        }
        seg[t] = lo;
    }
    __syncthreads();

    const int wave = t >> 6;
    const int lane = t & 63;
    const int sw = lane >> 5;
    const int sl = lane & 31;
    const int lb = sw << 5;
    const int rowbase = wave * 16;

    for (int it = 0; it < 8; ++it) {
        int cur_rb = rowbase + it * 2 + sw;
        int cur_r  = base + cur_rb;
        if (cur_r >= N) break;
        int cur_s = seg[cur_rb], cur_e = seg[cur_rb + 1];
        float4 a0 = make_float4(0.f, 0.f, 0.f, 0.f), a1 = a0;
        for (int cs = cur_s; cs < cur_e; cs += 32) {
            int m = cur_e - cs; if (m > 32) m = 32;
            int srcv = (cs + sl < cur_e) ? esrc[cs + sl] : 0;
            for (int j0 = 0; j0 < m; j0 += 8) {
                const int rem = m - j0;
#pragma unroll
                for (int u = 0; u < 8; ++u) {
                    int idx = __shfl(srcv, lb + ((j0 + u) & 31));
                    float4 v = *(const float4*)(x + (size_t)idx * FD + 4 * sl);
                    float f = (u < rem) ? 1.f : 0.f;
                    float4* A = (u & 1) ? &a1 : &a0;
                    A->x = fmaf(v.x, f, A->x);
                    A->y = fmaf(v.y, f, A->y);
                    A->z = fmaf(v.z, f, A->z);
                    A->w = fmaf(v.w, f, A->w);
                }
            }
        }
        float4 xv = *(const float4*)(x + (size_t)cur_r * FD + 4 * sl);
        int deg = cur_e - cur_s;
        float inv = 1.0f / (float)(deg > 0 ? deg : 1);
        short4 hb;
        hb.x = f2bf(xv.x + (a0.x + a1.x) * inv);
        hb.y = f2bf(xv.y + (a0.y + a1.y) * inv);
        hb.z = f2bf(xv.z + (a0.z + a1.z) * inv);
        hb.w = f2bf(xv.w + (a0.w + a1.w) * inv);
        *(short4*)(shb + cur_rb * HSB + 4 * sl) = hb;
    }
    __syncthreads();

    const int lr = lane & 15;
    const int q  = lane >> 4;
    const int colb = wave * 32;

    bf16x8 bfr[2][4];
#pragma unroll
    for (int ct = 0; ct < 2; ++ct) {
        int col = colb + ct * 16 + lr;
#pragma unroll
        for (int kt = 0; kt < 4; ++kt) {
            bf16x8 f;
#pragma unroll
            for (int e = 0; e < 8; ++e)
                f[e] = f2bf(W[(size_t)(kt * 32 + q * 8 + e) * FD + col]);
            bfr[ct][kt] = f;
        }
    }

    f32x4 acc[4][2];
#pragma unroll
    for (int rt = 0; rt < 4; ++rt) {
        acc[rt][0] = (f32x4){0.f, 0.f, 0.f, 0.f};
        acc[rt][1] = (f32x4){0.f, 0.f, 0.f, 0.f};
    }

#pragma unroll
    for (int rt = 0; rt < 4; ++rt)
#pragma unroll
        for (int kt = 0; kt < 4; ++kt) {
            bf16x8 av = *(const bf16x8*)(shb + (rt * 16 + lr) * HSB + kt * 32 + q * 8);
            acc[rt][0] = __builtin_amdgcn_mfma_f32_16x16x32_bf16(av, bfr[0][kt], acc[rt][0], 0, 0, 0);
            acc[rt][1] = __builtin_amdgcn_mfma_f32_16x16x32_bf16(av, bfr[1][kt], acc[rt][1], 0, 0, 0);
        }

    const float b0 = bias[colb + lr];
    const float b1 = bias[colb + 16 + lr];

#pragma unroll
    for (int rt = 0; rt < 4; ++rt)
#pragma unroll
        for (int j = 0; j < 4; ++j) {
            int row = base + rt * 16 + q * 4 + j;
            if (row < N) {
                float v0 = acc[rt][0][j] + b0; v0 = v0 > 0.f ? v0 : 0.f;
                float v1 = acc[rt][1][j] + b1; v1 = v1 > 0.f ? v1 : 0.f;
                out[(size_t)row * FD + colb + lr]      = v0;
                out[(size_t)row * FD + colb + 16 + lr] = v1;
            }
        }
}

extern "C" void kernel_launch(void* const* d_in, const int* in_sizes, int n_in,
                              void* d_out, int out_size, void* d_ws, size_t ws_size,
                              hipStream_t stream) {
    const float* x    = (const float*)d_in[0];
    const float* W    = (const float*)d_in[1];
    const float* bias = (const float*)d_in[2];
    const int* esrc   = (const int*)d_in[3];
    const int* edst   = (const int*)d_in[4];
    float* out        = (float*)d_out;

    int N = in_sizes[0] / FD;
    int E = in_sizes[3];
    int blocks = (N + BR - 1) / BR;

    size_t rp_bytes = (size_t)(N + 1) * 4;
    size_t pk_off   = (rp_bytes + 511) & ~(size_t)511;
    size_t xb_off   = (pk_off + 2048 * 8 * 2 + 511) & ~(size_t)511;
    size_t need_med = pk_off + 2048 * 8 * 2;
    size_t need_big = xb_off + (size_t)N * FD * 2;

    if (ws_size >= need_big) {
        int* rp    = (int*)d_ws;
        short* pkW = (short*)((char*)d_ws + pk_off);
        short* xb  = (short*)((char*)d_ws + xb_off);
        prep_full_kernel<<<2048, 256, 0, stream>>>(x, W, edst, rp, pkW, xb, N, E);
        meanagg_main2_kernel<<<blocks, 256, 0, stream>>>(xb, pkW, bias, esrc, rp, out, N, E);
    } else if (ws_size >= need_med) {
        int* rp    = (int*)d_ws;
        short* pkW = (short*)((char*)d_ws + pk_off);
        int pblocks = (E + 255) / 256;
        prep_kernel<<<pblocks, 256, 0, stream>>>(W, edst, rp, pkW, N, E);
        meanagg_main_kernel<<<blocks, 256, 0, stream>>>(x, pkW, bias, esrc, rp, out, N, E);
    } else {
        meanagg_fused_kernel<<<blocks, 256, 0, stream>>>(x, W, bias, esrc, edst, out, N, E);
    }
}